// Round 5
// baseline (312.896 us; speedup 1.0000x reference)
//
#include <hip/hip_runtime.h>
#include <hip/hip_cooperative_groups.h>
#include <math.h>

namespace cg = cooperative_groups;

#define Hh 72
#define Ww 128
#define HW (Hh*Ww)          // 9216 grid points
#define NP 24               // points per curve
#define NSEG (NP-1)
#define Mp 40               // pred curves
#define Ng 24               // gt curves
#define Bb 2                // batch
#define NRS 64
#define THICKc 0.03f
#define SHARPc 80.0f
#define NCURV (Bb*(Mp+Ng))  // 128 flat curves: [0,80)=pred, [80,128)=gt
#define NBLK 480            // = Bb * 20 * 12 (phase-3 tiles), also phase-1/2 pool
#define NCHUNK (HW/256)     // 36 grid chunks per curve

// ---------------------------------------------------------------------------
// Single cooperative kernel, 3 phases separated by grid.sync():
//   P1 (blocks 0..127): gt mask + fallback, arclength resample, compact
//       valid-segment list (point-fallback encoded as zero-length segments).
//   P2 (4608 tasks / 480 blocks): soft mask from compact segment list.
//   P3 (480 blocks, one 2x2 pair tile each): grid sums (union via
//       Sp+Sq-Smin identity) + per-wave Chamfer/tangent/curvature.
// Rationale (R3 post-mortem): kernel bodies total ~10us; the window is
// launch/reset-overhead dominated -> cut dispatches 3 -> 1.
// ---------------------------------------------------------------------------
__global__ __launch_bounds__(256) void k_fused(
    const float* __restrict__ pred,   // B*M*NP*2
    const float* __restrict__ gt,     // B*N*NP*2
    const float* __restrict__ vis,    // B*N*NP
    const float* __restrict__ gtExist,// B*N
    float* __restrict__ predRS,       // B*M*NRS*2
    float* __restrict__ gtRS,         // B*N*NRS*2
    float* __restrict__ segData,      // NCURV*NP*8
    int*   __restrict__ segCount,     // NCURV
    float* __restrict__ maskAll,      // NCURV*HW
    float* __restrict__ out)          // B*M*N
{
    cg::grid_group grid = cg::this_grid();
    int tid = threadIdx.x;

    // ======================= Phase 1: prep (blocks 0..127) ==================
    __shared__ float qx[NP], qy[NP], pm[NP], cum[NP];
    __shared__ int   sidx[NP];
    __shared__ int   s_mode;
    __shared__ float s_total;

    if (blockIdx.x < NCURV) {
        int c = blockIdx.x;
        bool isPred = (c < Bb * Mp);
        int b   = isPred ? (c / Mp) : ((c - Bb * Mp) / Ng);
        int idx = isPred ? (c % Mp) : ((c - Bb * Mp) % Ng);
        const float* src = isPred ? pred + (size_t)(b * Mp + idx) * NP * 2
                                  : gt   + (size_t)(b * Ng + idx) * NP * 2;
        if (tid < NP) {
            float2 v = ((const float2*)src)[tid];
            qx[tid] = v.x; qy[tid] = v.y;
            pm[tid] = isPred ? 1.0f
                             : ((vis[(b * Ng + idx) * NP + tid] > 0.5f) ? 1.0f : 0.0f);
        }
        __syncthreads();
        if (tid == 0) {
            if (!isPred) {
                float s = 0.0f;
                for (int p = 0; p < NP; p++) s += pm[p];
                if (s < 2.0f)                    // fallback: fewer than 2 visible
                    for (int p = 0; p < NP; p++) pm[p] = 1.0f;
            }
            float acc = 0.0f;
            cum[0] = 0.0f;
            for (int s = 0; s < NSEG; s++) {
                float dx = qx[s + 1] - qx[s], dy = qy[s + 1] - qy[s];
                acc += sqrtf(dx * dx + dy * dy) * (pm[s] * pm[s + 1]);
                cum[s + 1] = acc;
            }
            s_total = acc;
            int n = 0;
            for (int s = 0; s < NSEG; s++) sidx[s] = (pm[s] * pm[s + 1] > 0.5f) ? n++ : -1;
            if (n > 0) {
                s_mode = 0;
            } else {
                s_mode = 1;
                for (int p = 0; p < NP; p++) sidx[p] = (pm[p] > 0.5f) ? n++ : -1;
            }
            segCount[c] = n;
        }
        __syncthreads();

        if (s_mode == 0) {
            if (tid < NSEG && sidx[tid] >= 0) {
                float ax = qx[tid], ay = qy[tid];
                float abx = qx[tid + 1] - ax, aby = qy[tid + 1] - ay;
                float inv = 1.0f / fmaxf(abx * abx + aby * aby, 1e-8f);
                float* r = segData + ((size_t)c * NP + sidx[tid]) * 8;
                r[0] = ax;        r[1] = ay;        r[2] = abx; r[3] = aby;
                r[4] = abx * inv; r[5] = aby * inv;
                r[6] = (ax * abx + ay * aby) * inv; r[7] = 0.f;
            }
        } else {
            if (tid < NP && sidx[tid] >= 0) {
                float* r = segData + ((size_t)c * NP + sidx[tid]) * 8;
                r[0] = qx[tid]; r[1] = qy[tid]; r[2] = 0.f; r[3] = 0.f;
                r[4] = 0.f;     r[5] = 0.f;     r[6] = 0.f; r[7] = 0.f;
            }
        }

        // arclength resample (threads 0..63, one per output point)
        if (tid < NRS) {
            float total = s_total;
            float t = ((float)tid / 63.0f) * total;
            int cnt = 0;               // searchsorted right - 1 == count(cum<=t)-1
            for (int p = 0; p < NP; p++) cnt += (cum[p] <= t) ? 1 : 0;
            int id2 = cnt - 1;
            id2 = (id2 < 0) ? 0 : ((id2 > NP - 2) ? NP - 2 : id2);
            float lt = cum[id2], rt = cum[id2 + 1];
            float alpha = (t - lt) / fmaxf(rt - lt, 1e-8f);
            float ox = qx[id2] + alpha * (qx[id2 + 1] - qx[id2]);
            float oy = qy[id2] + alpha * (qy[id2 + 1] - qy[id2]);
            if (total < 1e-8f) { ox = qx[0]; oy = qy[0]; }
            float* dst = isPred ? predRS + ((size_t)(b * Mp + idx) * NRS + tid) * 2
                                : gtRS   + ((size_t)(b * Ng + idx) * NRS + tid) * 2;
            dst[0] = ox; dst[1] = oy;
        }
    }
    __threadfence();
    grid.sync();

    // ================= Phase 2: soft masks (4608 tasks / 480 blocks) ========
    for (int task = blockIdx.x; task < NCURV * NCHUNK; task += NBLK) {
        int c = task / NCHUNK;
        int g = (task % NCHUNK) * 256 + tid;
        int n = segCount[c];          // uniform
        const float4* sd = (const float4*)(segData + (size_t)c * NP * 8);

        float gx = (float)(g & (Ww - 1)) * (1.0f / 127.0f);
        float gy = (float)(g >> 7)       * (1.0f / 71.0f);

        float best2 = 1e30f;
        for (int s = 0; s < n; s++) {
            float4 A  = sd[s * 2];    // ax, ay, abx, aby
            float4 Bv = sd[s * 2 + 1];// ux, uy, c, -
            float t = fmaf(gx, Bv.x, fmaf(gy, Bv.y, -Bv.z));
            t = fminf(fmaxf(t, 0.0f), 1.0f);
            float dx = gx - fmaf(t, A.z, A.x);
            float dy = gy - fmaf(t, A.w, A.y);
            best2 = fminf(best2, fmaf(dx, dx, dy * dy));
        }
        float mind = sqrtf(best2);
        maskAll[(size_t)c * HW + g] = 1.0f / (1.0f + __expf((mind - THICKc) * SHARPc));
    }
    __threadfence();
    grid.sync();

    // ================= Phase 3: pair costs (2x2 tile per block) =============
    {
        int blk = blockIdx.x;            // Bb * 20 * 12 == NBLK
        int tj = blk % 12;
        int ti = (blk / 12) % 20;
        int b  = blk / (12 * 20);
        int i0 = ti * 2, j0 = tj * 2;
        int lane = tid & 63, w = tid >> 6;

        __shared__ float sPx[2][NRS], sPy[2][NRS], sGx[2][NRS], sGy[2][NRS];
        __shared__ float partA[4][8];    // [wave][sm00,sm01,sm10,sm11,sp0,sp1,sq0,sq1]
        __shared__ float cham[4][3];     // [pair][sym,tan,curv]

        {
            int ci = tid >> 6, pt = tid & 63;
            if (ci < 2) {
                float2 v = ((const float2*)predRS)[(b * Mp + i0 + ci) * NRS + pt];
                sPx[ci][pt] = v.x; sPy[ci][pt] = v.y;
            } else {
                int cj = ci - 2;
                float2 v = ((const float2*)gtRS)[(b * Ng + j0 + cj) * NRS + pt];
                sGx[cj][pt] = v.x; sGy[cj][pt] = v.y;
            }
        }
        __syncthreads();

        // ---- phase A: grid sums for 4 pairs in one pass ----
        const float4* P0 = (const float4*)(maskAll + (size_t)(b * Mp + i0)     * HW);
        const float4* P1 = (const float4*)(maskAll + (size_t)(b * Mp + i0 + 1) * HW);
        const float4* Q0 = (const float4*)(maskAll + (size_t)(Bb * Mp + b * Ng + j0)     * HW);
        const float4* Q1 = (const float4*)(maskAll + (size_t)(Bb * Mp + b * Ng + j0 + 1) * HW);
        float sm00 = 0, sm01 = 0, sm10 = 0, sm11 = 0;
        float sp0 = 0, sp1 = 0, sq0 = 0, sq1 = 0;
        for (int g = tid; g < HW / 4; g += 256) {      // 9 iterations exact
            float4 p0 = P0[g], p1 = P1[g], q0 = Q0[g], q1 = Q1[g];
            sp0 += p0.x + p0.y + p0.z + p0.w;
            sp1 += p1.x + p1.y + p1.z + p1.w;
            sq0 += q0.x + q0.y + q0.z + q0.w;
            sq1 += q1.x + q1.y + q1.z + q1.w;
            sm00 += fminf(p0.x,q0.x) + fminf(p0.y,q0.y) + fminf(p0.z,q0.z) + fminf(p0.w,q0.w);
            sm01 += fminf(p0.x,q1.x) + fminf(p0.y,q1.y) + fminf(p0.z,q1.z) + fminf(p0.w,q1.w);
            sm10 += fminf(p1.x,q0.x) + fminf(p1.y,q0.y) + fminf(p1.z,q0.z) + fminf(p1.w,q0.w);
            sm11 += fminf(p1.x,q1.x) + fminf(p1.y,q1.y) + fminf(p1.z,q1.z) + fminf(p1.w,q1.w);
        }
        for (int off = 32; off > 0; off >>= 1) {
            sm00 += __shfl_down(sm00, off); sm01 += __shfl_down(sm01, off);
            sm10 += __shfl_down(sm10, off); sm11 += __shfl_down(sm11, off);
            sp0  += __shfl_down(sp0,  off); sp1  += __shfl_down(sp1,  off);
            sq0  += __shfl_down(sq0,  off); sq1  += __shfl_down(sq1,  off);
        }
        if (lane == 0) {
            partA[w][0] = sm00; partA[w][1] = sm01; partA[w][2] = sm10; partA[w][3] = sm11;
            partA[w][4] = sp0;  partA[w][5] = sp1;  partA[w][6] = sq0;  partA[w][7] = sq1;
        }

        // ---- phase B: wave w owns pair (a = w>>1, cj = w&1) ----
        {
            int a = w >> 1, cj = w & 1;
            const float* PX = sPx[a];  const float* PY = sPy[a];
            const float* GX = sGx[cj]; const float* GY = sGy[cj];
            float p0x = PX[lane], p0y = PY[lane];
            float q0x = GX[lane], q0y = GY[lane];
            float b1 = 1e30f, b2 = 1e30f;
            for (int s = 0; s < NRS - 1; s++) {
                {   // pred point -> gt segment s
                    float ax = GX[s], ay = GY[s];
                    float abx = GX[s + 1] - ax, aby = GY[s + 1] - ay;
                    float denom = fmaxf(abx * abx + aby * aby, 1e-8f);
                    float t = ((p0x - ax) * abx + (p0y - ay) * aby) / denom;
                    t = fminf(fmaxf(t, 0.0f), 1.0f);
                    float dx = p0x - (ax + t * abx), dy = p0y - (ay + t * aby);
                    b1 = fminf(b1, dx * dx + dy * dy);
                }
                {   // gt point -> pred segment s
                    float ax = PX[s], ay = PY[s];
                    float abx = PX[s + 1] - ax, aby = PY[s + 1] - ay;
                    float denom = fmaxf(abx * abx + aby * aby, 1e-8f);
                    float t = ((q0x - ax) * abx + (q0y - ay) * aby) / denom;
                    t = fminf(fmaxf(t, 0.0f), 1.0f);
                    float dx = q0x - (ax + t * abx), dy = q0y - (ay + t * aby);
                    b2 = fminf(b2, dx * dx + dy * dy);
                }
            }
            float symv = 0.5f * (sqrtf(b1) + sqrtf(b2));

            int kp = (lane == NRS - 1) ? NRS - 1 : lane + 1;
            int km = (lane == 0) ? 0 : lane - 1;
            float tx = PX[kp] - PX[km], ty = PY[kp] - PY[km];
            float nrm = fmaxf(sqrtf(tx * tx + ty * ty), 1e-8f);
            tx /= nrm; ty /= nrm;
            float gtx = GX[kp] - GX[km], gty = GY[kp] - GY[km];
            float nrm2 = fmaxf(sqrtf(gtx * gtx + gty * gty), 1e-8f);
            gtx /= nrm2; gty /= nrm2;
            float tanv = fabsf(tx * gtx + ty * gty);

            float curvv = 0.0f;
            if (lane < NRS - 2) {
                float psx = PX[lane + 2] - 2.0f * PX[lane + 1] + PX[lane];
                float psy = PY[lane + 2] - 2.0f * PY[lane + 1] + PY[lane];
                float gsx = GX[lane + 2] - 2.0f * GX[lane + 1] + GX[lane];
                float gsy = GY[lane + 2] - 2.0f * GY[lane + 1] + GY[lane];
                float d1 = fabsf(psx - gsx);
                float d2 = fabsf(psy - gsy);
                float c1 = (d1 < 1.0f) ? 0.5f * d1 * d1 : d1 - 0.5f;
                float c2 = (d2 < 1.0f) ? 0.5f * d2 * d2 : d2 - 0.5f;
                curvv = c1 + c2;
            }
            for (int off = 32; off > 0; off >>= 1) {
                symv  += __shfl_down(symv,  off);
                tanv  += __shfl_down(tanv,  off);
                curvv += __shfl_down(curvv, off);
            }
            if (lane == 0) { cham[w][0] = symv; cham[w][1] = tanv; cham[w][2] = curvv; }
        }
        __syncthreads();

        if (tid < 4) {
            int a2 = tid >> 1, c2 = tid & 1;
            float Smin = partA[0][tid] + partA[1][tid] + partA[2][tid] + partA[3][tid];
            float Sp = partA[0][4 + a2] + partA[1][4 + a2] + partA[2][4 + a2] + partA[3][4 + a2];
            float Sq = partA[0][6 + c2] + partA[1][6 + c2] + partA[2][6 + c2] + partA[3][6 + c2];
            float Smax = Sp + Sq - Smin;          // min+max == p+q
            float overlap = 1.0f - Smin / (Smax + 1e-8f);
            float sym  = cham[tid][0] * (1.0f / 64.0f);
            float tanl = 1.0f - cham[tid][1] * (1.0f / 64.0f);
            float curv = cham[tid][2] * (1.0f / 124.0f);
            float cost = 5.0f * sym + 1.0f * tanl + 0.5f * curv + 2.0f * overlap;
            float e = (gtExist[b * Ng + j0 + c2] > 0.5f) ? 1.0f : 0.0f;
            out[(size_t)(b * Mp + i0 + a2) * Ng + j0 + c2] = cost * e;
        }
    }
}

// ---------------------------------------------------------------------------
extern "C" void kernel_launch(void* const* d_in, const int* in_sizes, int n_in,
                              void* d_out, int out_size, void* d_ws, size_t ws_size,
                              hipStream_t stream) {
    (void)in_sizes; (void)n_in; (void)out_size; (void)ws_size;
    const float* pred  = (const float*)d_in[0];   // (2,40,24,2)
    const float* gt    = (const float*)d_in[1];   // (2,24,24,2)
    const float* vis   = (const float*)d_in[2];   // (2,24,24)
    const float* exist = (const float*)d_in[3];   // (2,24)

    float* ws      = (float*)d_ws;
    float* predRS  = ws;                                   // 10240
    float* gtRS    = predRS + (size_t)Bb * Mp * NRS * 2;   // 6144
    float* segData = gtRS   + (size_t)Bb * Ng * NRS * 2;   // 128*24*8 = 24576
    int*   segCount= (int*)(segData + (size_t)NCURV * NP * 8);  // 128 ints
    float* maskAll = (float*)(segCount + 128);             // 128*9216 floats
    float* outp    = (float*)d_out;

    void* args[] = { (void*)&pred, (void*)&gt, (void*)&vis, (void*)&exist,
                     (void*)&predRS, (void*)&gtRS, (void*)&segData,
                     (void*)&segCount, (void*)&maskAll, (void*)&outp };
    hipLaunchCooperativeKernel((void*)k_fused, dim3(NBLK), dim3(256),
                               args, 0, stream);
}

// Round 6
// 109.340 us; speedup vs baseline: 2.8617x; 2.8617x over previous
//
#include <hip/hip_runtime.h>
#include <math.h>

#define Hh 72
#define Ww 128
#define HW (Hh*Ww)          // 9216 grid points
#define NP 24               // points per curve
#define NSEG (NP-1)
#define Mp 40               // pred curves
#define Ng 24               // gt curves
#define Bb 2                // batch
#define NRS 64
#define THICKc 0.03f
#define SHARPc 80.0f
#define NCURV (Bb*(Mp+Ng))  // 128 flat curves: [0,80)=pred, [80,128)=gt
#define NCHUNK (HW/256)     // 36 grid chunks per curve

// ---------------------------------------------------------------------------
// K_A: fused prep + soft mask. grid = (NCHUNK, NCURV), 256 threads.
// Every block redundantly computes its curve's visibility mask + compact
// valid-segment list IN LDS (~300 serial cycles — cheaper than a dispatch;
// R4 post-mortem: cg::grid.sync costs ~115us on gfx950, never again).
// Point-fallback encoded as zero-length segments (ab=0 -> t=0 -> point dist).
// Chunk-0 blocks additionally write the arclength resample for K_B.
// ---------------------------------------------------------------------------
__global__ __launch_bounds__(256) void k_mask(
    const float* __restrict__ pred,   // B*M*NP*2
    const float* __restrict__ gt,     // B*N*NP*2
    const float* __restrict__ vis,    // B*N*NP
    float* __restrict__ predRS,       // B*M*NRS*2
    float* __restrict__ gtRS,         // B*N*NRS*2
    float* __restrict__ maskAll)      // NCURV*HW
{
    int c = blockIdx.y;               // flat curve id
    bool isPred = (c < Bb * Mp);
    int b   = isPred ? (c / Mp) : ((c - Bb * Mp) / Ng);
    int idx = isPred ? (c % Mp) : ((c - Bb * Mp) % Ng);
    const float* src = isPred ? pred + (size_t)(b * Mp + idx) * NP * 2
                              : gt   + (size_t)(b * Ng + idx) * NP * 2;
    int tid = threadIdx.x;

    __shared__ float qx[NP], qy[NP], pm[NP], cum[NP];
    __shared__ float4 segA[NP], segB[NP];   // ax,ay,abx,aby | ux,uy,c,-
    __shared__ int   s_n;
    __shared__ float s_total;

    if (tid < NP) {
        float2 v = ((const float2*)src)[tid];
        qx[tid] = v.x; qy[tid] = v.y;
        pm[tid] = isPred ? 1.0f
                         : ((vis[(b * Ng + idx) * NP + tid] > 0.5f) ? 1.0f : 0.0f);
    }
    __syncthreads();
    if (tid == 0) {
        if (!isPred) {
            float s = 0.0f;
            for (int p = 0; p < NP; p++) s += pm[p];
            if (s < 2.0f)                    // fallback: fewer than 2 visible
                for (int p = 0; p < NP; p++) pm[p] = 1.0f;
        }
        // arclength cumsum (only consumed by chunk-0 resample; cheap)
        float acc = 0.0f;
        cum[0] = 0.0f;
        for (int s = 0; s < NSEG; s++) {
            float dx = qx[s + 1] - qx[s], dy = qy[s + 1] - qy[s];
            acc += sqrtf(dx * dx + dy * dy) * (pm[s] * pm[s + 1]);
            cum[s + 1] = acc;
        }
        s_total = acc;
        // compact valid-segment records into LDS
        int n = 0;
        for (int s = 0; s < NSEG; s++) {
            if (pm[s] * pm[s + 1] > 0.5f) {
                float ax = qx[s], ay = qy[s];
                float abx = qx[s + 1] - ax, aby = qy[s + 1] - ay;
                float inv = 1.0f / fmaxf(abx * abx + aby * aby, 1e-8f);
                segA[n] = make_float4(ax, ay, abx, aby);
                segB[n] = make_float4(abx * inv, aby * inv,
                                      (ax * abx + ay * aby) * inv, 0.f);
                n++;
            }
        }
        if (n == 0) {                        // point fallback: zero-length segs
            for (int p = 0; p < NP; p++) {
                if (pm[p] > 0.5f) {
                    segA[n] = make_float4(qx[p], qy[p], 0.f, 0.f);
                    segB[n] = make_float4(0.f, 0.f, 0.f, 0.f);
                    n++;
                }
            }
        }
        s_n = n;
    }
    __syncthreads();

    // chunk-0 block also writes the resample (threads 0..63)
    if (blockIdx.x == 0 && tid < NRS) {
        float total = s_total;
        float t = ((float)tid / 63.0f) * total;
        int cnt = 0;                   // searchsorted right - 1 == count(cum<=t)-1
        for (int p = 0; p < NP; p++) cnt += (cum[p] <= t) ? 1 : 0;
        int id2 = cnt - 1;
        id2 = (id2 < 0) ? 0 : ((id2 > NP - 2) ? NP - 2 : id2);
        float lt = cum[id2], rt = cum[id2 + 1];
        float alpha = (t - lt) / fmaxf(rt - lt, 1e-8f);
        float ox = qx[id2] + alpha * (qx[id2 + 1] - qx[id2]);
        float oy = qy[id2] + alpha * (qy[id2 + 1] - qy[id2]);
        if (total < 1e-8f) { ox = qx[0]; oy = qy[0]; }
        float* dst = isPred ? predRS + ((size_t)(b * Mp + idx) * NRS + tid) * 2
                            : gtRS   + ((size_t)(b * Ng + idx) * NRS + tid) * 2;
        dst[0] = ox; dst[1] = oy;
    }

    // soft mask for this block's 256 grid points (LDS broadcast reads)
    int g = blockIdx.x * 256 + tid;
    float gx = (float)(g & (Ww - 1)) * (1.0f / 127.0f);
    float gy = (float)(g >> 7)       * (1.0f / 71.0f);
    int n = s_n;
    float best2 = 1e30f;
    for (int s = 0; s < n; s++) {
        float4 A  = segA[s];
        float4 Bv = segB[s];
        float t = fmaf(gx, Bv.x, fmaf(gy, Bv.y, -Bv.z));
        t = fminf(fmaxf(t, 0.0f), 1.0f);
        float dx = gx - fmaf(t, A.z, A.x);
        float dy = gy - fmaf(t, A.w, A.y);
        best2 = fminf(best2, fmaf(dx, dx, dy * dy));
    }
    float mind = sqrtf(best2);
    maskAll[(size_t)c * HW + g] = 1.0f / (1.0f + __expf((mind - THICKc) * SHARPc));
}

// ---------------------------------------------------------------------------
// K_B: 2x2 pair tile per block (480 blocks, 256 threads). Phase A: one pass
// over the grid reads 4 mask rows for 4 pairs; union via Sp+Sq-Smin identity.
// Phase B: each wave owns one pair's Chamfer/tangent/curvature.
// ---------------------------------------------------------------------------
__global__ __launch_bounds__(256) void k_cost(
    const float* __restrict__ predRS,
    const float* __restrict__ gtRS,
    const float* __restrict__ maskAll,
    const float* __restrict__ gtExist,   // B*N
    float* __restrict__ out)             // B*M*N
{
    int blk = blockIdx.x;                // Bb * 20 * 12
    int tj = blk % 12;
    int ti = (blk / 12) % 20;
    int b  = blk / (12 * 20);
    int i0 = ti * 2, j0 = tj * 2;
    int tid = threadIdx.x;
    int lane = tid & 63, w = tid >> 6;

    __shared__ float sPx[2][NRS], sPy[2][NRS], sGx[2][NRS], sGy[2][NRS];
    __shared__ float partA[4][8];        // [wave][sm00,sm01,sm10,sm11,sp0,sp1,sq0,sq1]
    __shared__ float cham[4][3];         // [pair][sym,tan,curv]

    {
        int ci = tid >> 6, pt = tid & 63;
        if (ci < 2) {
            float2 v = ((const float2*)predRS)[(b * Mp + i0 + ci) * NRS + pt];
            sPx[ci][pt] = v.x; sPy[ci][pt] = v.y;
        } else {
            int cj = ci - 2;
            float2 v = ((const float2*)gtRS)[(b * Ng + j0 + cj) * NRS + pt];
            sGx[cj][pt] = v.x; sGy[cj][pt] = v.y;
        }
    }
    __syncthreads();

    // ---- phase A: grid sums for 4 pairs in one pass ----
    const float4* P0 = (const float4*)(maskAll + (size_t)(b * Mp + i0)     * HW);
    const float4* P1 = (const float4*)(maskAll + (size_t)(b * Mp + i0 + 1) * HW);
    const float4* Q0 = (const float4*)(maskAll + (size_t)(Bb * Mp + b * Ng + j0)     * HW);
    const float4* Q1 = (const float4*)(maskAll + (size_t)(Bb * Mp + b * Ng + j0 + 1) * HW);
    float sm00 = 0, sm01 = 0, sm10 = 0, sm11 = 0;
    float sp0 = 0, sp1 = 0, sq0 = 0, sq1 = 0;
    for (int g = tid; g < HW / 4; g += 256) {      // 9 iterations exact
        float4 p0 = P0[g], p1 = P1[g], q0 = Q0[g], q1 = Q1[g];
        sp0 += p0.x + p0.y + p0.z + p0.w;
        sp1 += p1.x + p1.y + p1.z + p1.w;
        sq0 += q0.x + q0.y + q0.z + q0.w;
        sq1 += q1.x + q1.y + q1.z + q1.w;
        sm00 += fminf(p0.x,q0.x) + fminf(p0.y,q0.y) + fminf(p0.z,q0.z) + fminf(p0.w,q0.w);
        sm01 += fminf(p0.x,q1.x) + fminf(p0.y,q1.y) + fminf(p0.z,q1.z) + fminf(p0.w,q1.w);
        sm10 += fminf(p1.x,q0.x) + fminf(p1.y,q0.y) + fminf(p1.z,q0.z) + fminf(p1.w,q0.w);
        sm11 += fminf(p1.x,q1.x) + fminf(p1.y,q1.y) + fminf(p1.z,q1.z) + fminf(p1.w,q1.w);
    }
    for (int off = 32; off > 0; off >>= 1) {
        sm00 += __shfl_down(sm00, off); sm01 += __shfl_down(sm01, off);
        sm10 += __shfl_down(sm10, off); sm11 += __shfl_down(sm11, off);
        sp0  += __shfl_down(sp0,  off); sp1  += __shfl_down(sp1,  off);
        sq0  += __shfl_down(sq0,  off); sq1  += __shfl_down(sq1,  off);
    }
    if (lane == 0) {
        partA[w][0] = sm00; partA[w][1] = sm01; partA[w][2] = sm10; partA[w][3] = sm11;
        partA[w][4] = sp0;  partA[w][5] = sp1;  partA[w][6] = sq0;  partA[w][7] = sq1;
    }

    // ---- phase B: wave w owns pair (a = w>>1, cj = w&1) ----
    {
        int a = w >> 1, cj = w & 1;
        const float* PX = sPx[a];  const float* PY = sPy[a];
        const float* GX = sGx[cj]; const float* GY = sGy[cj];
        float p0x = PX[lane], p0y = PY[lane];
        float q0x = GX[lane], q0y = GY[lane];
        float b1 = 1e30f, b2 = 1e30f;
        for (int s = 0; s < NRS - 1; s++) {
            {   // pred point -> gt segment s
                float ax = GX[s], ay = GY[s];
                float abx = GX[s + 1] - ax, aby = GY[s + 1] - ay;
                float denom = fmaxf(abx * abx + aby * aby, 1e-8f);
                float t = ((p0x - ax) * abx + (p0y - ay) * aby) / denom;
                t = fminf(fmaxf(t, 0.0f), 1.0f);
                float dx = p0x - (ax + t * abx), dy = p0y - (ay + t * aby);
                b1 = fminf(b1, dx * dx + dy * dy);
            }
            {   // gt point -> pred segment s
                float ax = PX[s], ay = PY[s];
                float abx = PX[s + 1] - ax, aby = PY[s + 1] - ay;
                float denom = fmaxf(abx * abx + aby * aby, 1e-8f);
                float t = ((q0x - ax) * abx + (q0y - ay) * aby) / denom;
                t = fminf(fmaxf(t, 0.0f), 1.0f);
                float dx = q0x - (ax + t * abx), dy = q0y - (ay + t * aby);
                b2 = fminf(b2, dx * dx + dy * dy);
            }
        }
        float symv = 0.5f * (sqrtf(b1) + sqrtf(b2));

        int kp = (lane == NRS - 1) ? NRS - 1 : lane + 1;
        int km = (lane == 0) ? 0 : lane - 1;
        float tx = PX[kp] - PX[km], ty = PY[kp] - PY[km];
        float nrm = fmaxf(sqrtf(tx * tx + ty * ty), 1e-8f);
        tx /= nrm; ty /= nrm;
        float gtx = GX[kp] - GX[km], gty = GY[kp] - GY[km];
        float nrm2 = fmaxf(sqrtf(gtx * gtx + gty * gty), 1e-8f);
        gtx /= nrm2; gty /= nrm2;
        float tanv = fabsf(tx * gtx + ty * gty);

        float curvv = 0.0f;
        if (lane < NRS - 2) {
            float psx = PX[lane + 2] - 2.0f * PX[lane + 1] + PX[lane];
            float psy = PY[lane + 2] - 2.0f * PY[lane + 1] + PY[lane];
            float gsx = GX[lane + 2] - 2.0f * GX[lane + 1] + GX[lane];
            float gsy = GY[lane + 2] - 2.0f * GY[lane + 1] + GY[lane];
            float d1 = fabsf(psx - gsx);
            float d2 = fabsf(psy - gsy);
            float c1 = (d1 < 1.0f) ? 0.5f * d1 * d1 : d1 - 0.5f;
            float c2 = (d2 < 1.0f) ? 0.5f * d2 * d2 : d2 - 0.5f;
            curvv = c1 + c2;
        }
        for (int off = 32; off > 0; off >>= 1) {
            symv  += __shfl_down(symv,  off);
            tanv  += __shfl_down(tanv,  off);
            curvv += __shfl_down(curvv, off);
        }
        if (lane == 0) { cham[w][0] = symv; cham[w][1] = tanv; cham[w][2] = curvv; }
    }
    __syncthreads();

    if (tid < 4) {
        int a2 = tid >> 1, c2 = tid & 1;
        float Smin = partA[0][tid] + partA[1][tid] + partA[2][tid] + partA[3][tid];
        float Sp = partA[0][4 + a2] + partA[1][4 + a2] + partA[2][4 + a2] + partA[3][4 + a2];
        float Sq = partA[0][6 + c2] + partA[1][6 + c2] + partA[2][6 + c2] + partA[3][6 + c2];
        float Smax = Sp + Sq - Smin;          // min+max == p+q
        float overlap = 1.0f - Smin / (Smax + 1e-8f);
        float sym  = cham[tid][0] * (1.0f / 64.0f);
        float tanl = 1.0f - cham[tid][1] * (1.0f / 64.0f);
        float curv = cham[tid][2] * (1.0f / 124.0f);
        float cost = 5.0f * sym + 1.0f * tanl + 0.5f * curv + 2.0f * overlap;
        float e = (gtExist[b * Ng + j0 + c2] > 0.5f) ? 1.0f : 0.0f;
        out[(size_t)(b * Mp + i0 + a2) * Ng + j0 + c2] = cost * e;
    }
}

// ---------------------------------------------------------------------------
extern "C" void kernel_launch(void* const* d_in, const int* in_sizes, int n_in,
                              void* d_out, int out_size, void* d_ws, size_t ws_size,
                              hipStream_t stream) {
    (void)in_sizes; (void)n_in; (void)out_size; (void)ws_size;
    const float* pred  = (const float*)d_in[0];   // (2,40,24,2)
    const float* gt    = (const float*)d_in[1];   // (2,24,24,2)
    const float* vis   = (const float*)d_in[2];   // (2,24,24)
    const float* exist = (const float*)d_in[3];   // (2,24)

    float* ws      = (float*)d_ws;
    float* predRS  = ws;                                   // 10240
    float* gtRS    = predRS + (size_t)Bb * Mp * NRS * 2;   // 6144
    float* maskAll = gtRS   + (size_t)Bb * Ng * NRS * 2;   // 128*9216 floats
    float* outp    = (float*)d_out;

    hipLaunchKernelGGL(k_mask, dim3(NCHUNK, NCURV), dim3(256), 0, stream,
                       pred, gt, vis, predRS, gtRS, maskAll);
    hipLaunchKernelGGL(k_cost, dim3(Bb * 20 * 12), dim3(256), 0, stream,
                       predRS, gtRS, maskAll, exist, outp);
}

// Round 7
// 93.944 us; speedup vs baseline: 3.3307x; 1.1639x over previous
//
#include <hip/hip_runtime.h>
#include <math.h>

#define Hh 72
#define Ww 128
#define HW (Hh*Ww)          // 9216 grid points
#define NP 24               // points per curve
#define NSEG (NP-1)
#define Mp 40               // pred curves
#define Ng 24               // gt curves
#define Bb 2                // batch
#define NRS 64
#define THICKc 0.03f
#define SHARPc 80.0f
#define NCURV (Bb*(Mp+Ng))  // 128 flat curves: [0,80)=pred, [80,128)=gt
#define GPT 4               // grid points per thread in k_mask
#define XBLK (HW/(256*GPT)) // 9 x-blocks per curve

// ---------------------------------------------------------------------------
// K_A: fused prep + soft mask. grid = (XBLK, NCURV), 256 threads, 4 grid
// points per thread (consecutive -> float4 store, 4x LDS-read reuse).
// Per-block prep (visibility+fallback, compact valid segments) runs on
// thread 0 (~500 cyc, amortized over 1024 grid points/block).
// Point-fallback encoded as zero-length segments (ab=0 -> t=0 -> point dist).
// Chunk-0 blocks also write the arclength resample.
// R4 lesson: never cg::grid.sync (~115us); R5 lesson: keep LDS reads per
// segment amortized across multiple grid points.
// ---------------------------------------------------------------------------
__global__ __launch_bounds__(256) void k_mask(
    const float* __restrict__ pred,   // B*M*NP*2
    const float* __restrict__ gt,     // B*N*NP*2
    const float* __restrict__ vis,    // B*N*NP
    float* __restrict__ predRS,       // B*M*NRS*2
    float* __restrict__ gtRS,         // B*N*NRS*2
    float* __restrict__ maskAll)      // NCURV*HW
{
    int c = blockIdx.y;               // flat curve id
    bool isPred = (c < Bb * Mp);
    int b   = isPred ? (c / Mp) : ((c - Bb * Mp) / Ng);
    int idx = isPred ? (c % Mp) : ((c - Bb * Mp) % Ng);
    const float* src = isPred ? pred + (size_t)(b * Mp + idx) * NP * 2
                              : gt   + (size_t)(b * Ng + idx) * NP * 2;
    int tid = threadIdx.x;

    __shared__ float qx[NP], qy[NP], pm[NP], cum[NP];
    __shared__ float4 segA[NP], segB[NP];   // ax,ay,abx,aby | ux,uy,c,-
    __shared__ int   s_n;
    __shared__ float s_total;

    if (tid < NP) {
        float2 v = ((const float2*)src)[tid];
        qx[tid] = v.x; qy[tid] = v.y;
        pm[tid] = isPred ? 1.0f
                         : ((vis[(b * Ng + idx) * NP + tid] > 0.5f) ? 1.0f : 0.0f);
    }
    __syncthreads();
    if (tid == 0) {
        if (!isPred) {
            float s = 0.0f;
            for (int p = 0; p < NP; p++) s += pm[p];
            if (s < 2.0f)                    // fallback: fewer than 2 visible
                for (int p = 0; p < NP; p++) pm[p] = 1.0f;
        }
        float acc = 0.0f;
        cum[0] = 0.0f;
        for (int s = 0; s < NSEG; s++) {
            float dx = qx[s + 1] - qx[s], dy = qy[s + 1] - qy[s];
            acc += sqrtf(dx * dx + dy * dy) * (pm[s] * pm[s + 1]);
            cum[s + 1] = acc;
        }
        s_total = acc;
        int n = 0;
        for (int s = 0; s < NSEG; s++) {
            if (pm[s] * pm[s + 1] > 0.5f) {
                float ax = qx[s], ay = qy[s];
                float abx = qx[s + 1] - ax, aby = qy[s + 1] - ay;
                float inv = 1.0f / fmaxf(abx * abx + aby * aby, 1e-8f);
                segA[n] = make_float4(ax, ay, abx, aby);
                segB[n] = make_float4(abx * inv, aby * inv,
                                      (ax * abx + ay * aby) * inv, 0.f);
                n++;
            }
        }
        if (n == 0) {                        // point fallback: zero-length segs
            for (int p = 0; p < NP; p++) {
                if (pm[p] > 0.5f) {
                    segA[n] = make_float4(qx[p], qy[p], 0.f, 0.f);
                    segB[n] = make_float4(0.f, 0.f, 0.f, 0.f);
                    n++;
                }
            }
        }
        s_n = n;
    }
    __syncthreads();

    // chunk-0 block also writes the resample (threads 0..63)
    if (blockIdx.x == 0 && tid < NRS) {
        float total = s_total;
        float t = ((float)tid / 63.0f) * total;
        int cnt = 0;                   // searchsorted right - 1 == count(cum<=t)-1
        for (int p = 0; p < NP; p++) cnt += (cum[p] <= t) ? 1 : 0;
        int id2 = cnt - 1;
        id2 = (id2 < 0) ? 0 : ((id2 > NP - 2) ? NP - 2 : id2);
        float lt = cum[id2], rt = cum[id2 + 1];
        float alpha = (t - lt) / fmaxf(rt - lt, 1e-8f);
        float ox = qx[id2] + alpha * (qx[id2 + 1] - qx[id2]);
        float oy = qy[id2] + alpha * (qy[id2 + 1] - qy[id2]);
        if (total < 1e-8f) { ox = qx[0]; oy = qy[0]; }
        float* dst = isPred ? predRS + ((size_t)(b * Mp + idx) * NRS + tid) * 2
                            : gtRS   + ((size_t)(b * Ng + idx) * NRS + tid) * 2;
        dst[0] = ox; dst[1] = oy;
    }

    // soft mask: 4 consecutive grid points per thread, one float4 store
    int g0 = blockIdx.x * (256 * GPT) + tid * GPT;
    float gxv[GPT], gyv[GPT], bst[GPT];
    #pragma unroll
    for (int k = 0; k < GPT; k++) {
        int g = g0 + k;
        gxv[k] = (float)(g & (Ww - 1)) * (1.0f / 127.0f);
        gyv[k] = (float)(g >> 7)       * (1.0f / 71.0f);
        bst[k] = 1e30f;
    }
    int n = s_n;
    for (int s = 0; s < n; s++) {
        float4 A  = segA[s];          // 2 LDS reads per segment, reused 4x
        float4 Bv = segB[s];
        #pragma unroll
        for (int k = 0; k < GPT; k++) {
            float t = fmaf(gxv[k], Bv.x, fmaf(gyv[k], Bv.y, -Bv.z));
            t = fminf(fmaxf(t, 0.0f), 1.0f);
            float dx = gxv[k] - fmaf(t, A.z, A.x);
            float dy = gyv[k] - fmaf(t, A.w, A.y);
            bst[k] = fminf(bst[k], fmaf(dx, dx, dy * dy));
        }
    }
    float4 mout;
    mout.x = 1.0f / (1.0f + __expf((sqrtf(bst[0]) - THICKc) * SHARPc));
    mout.y = 1.0f / (1.0f + __expf((sqrtf(bst[1]) - THICKc) * SHARPc));
    mout.z = 1.0f / (1.0f + __expf((sqrtf(bst[2]) - THICKc) * SHARPc));
    mout.w = 1.0f / (1.0f + __expf((sqrtf(bst[3]) - THICKc) * SHARPc));
    *(float4*)(maskAll + (size_t)c * HW + g0) = mout;
}

// ---------------------------------------------------------------------------
// K_B: 2x2 pair tile per block (480 blocks, 256 threads). Phase A: one pass
// over the grid reads 4 mask rows for 4 pairs; union via Sp+Sq-Smin identity.
// Phase B: each wave owns one pair's Chamfer/tangent/curvature.
// ---------------------------------------------------------------------------
__global__ __launch_bounds__(256) void k_cost(
    const float* __restrict__ predRS,
    const float* __restrict__ gtRS,
    const float* __restrict__ maskAll,
    const float* __restrict__ gtExist,   // B*N
    float* __restrict__ out)             // B*M*N
{
    int blk = blockIdx.x;                // Bb * 20 * 12
    int tj = blk % 12;
    int ti = (blk / 12) % 20;
    int b  = blk / (12 * 20);
    int i0 = ti * 2, j0 = tj * 2;
    int tid = threadIdx.x;
    int lane = tid & 63, w = tid >> 6;

    __shared__ float sPx[2][NRS], sPy[2][NRS], sGx[2][NRS], sGy[2][NRS];
    __shared__ float partA[4][8];        // [wave][sm00,sm01,sm10,sm11,sp0,sp1,sq0,sq1]
    __shared__ float cham[4][3];         // [pair][sym,tan,curv]

    {
        int ci = tid >> 6, pt = tid & 63;
        if (ci < 2) {
            float2 v = ((const float2*)predRS)[(b * Mp + i0 + ci) * NRS + pt];
            sPx[ci][pt] = v.x; sPy[ci][pt] = v.y;
        } else {
            int cj = ci - 2;
            float2 v = ((const float2*)gtRS)[(b * Ng + j0 + cj) * NRS + pt];
            sGx[cj][pt] = v.x; sGy[cj][pt] = v.y;
        }
    }
    __syncthreads();

    // ---- phase A: grid sums for 4 pairs in one pass ----
    const float4* P0 = (const float4*)(maskAll + (size_t)(b * Mp + i0)     * HW);
    const float4* P1 = (const float4*)(maskAll + (size_t)(b * Mp + i0 + 1) * HW);
    const float4* Q0 = (const float4*)(maskAll + (size_t)(Bb * Mp + b * Ng + j0)     * HW);
    const float4* Q1 = (const float4*)(maskAll + (size_t)(Bb * Mp + b * Ng + j0 + 1) * HW);
    float sm00 = 0, sm01 = 0, sm10 = 0, sm11 = 0;
    float sp0 = 0, sp1 = 0, sq0 = 0, sq1 = 0;
    for (int g = tid; g < HW / 4; g += 256) {      // 9 iterations exact
        float4 p0 = P0[g], p1 = P1[g], q0 = Q0[g], q1 = Q1[g];
        sp0 += p0.x + p0.y + p0.z + p0.w;
        sp1 += p1.x + p1.y + p1.z + p1.w;
        sq0 += q0.x + q0.y + q0.z + q0.w;
        sq1 += q1.x + q1.y + q1.z + q1.w;
        sm00 += fminf(p0.x,q0.x) + fminf(p0.y,q0.y) + fminf(p0.z,q0.z) + fminf(p0.w,q0.w);
        sm01 += fminf(p0.x,q1.x) + fminf(p0.y,q1.y) + fminf(p0.z,q1.z) + fminf(p0.w,q1.w);
        sm10 += fminf(p1.x,q0.x) + fminf(p1.y,q0.y) + fminf(p1.z,q0.z) + fminf(p1.w,q0.w);
        sm11 += fminf(p1.x,q1.x) + fminf(p1.y,q1.y) + fminf(p1.z,q1.z) + fminf(p1.w,q1.w);
    }
    for (int off = 32; off > 0; off >>= 1) {
        sm00 += __shfl_down(sm00, off); sm01 += __shfl_down(sm01, off);
        sm10 += __shfl_down(sm10, off); sm11 += __shfl_down(sm11, off);
        sp0  += __shfl_down(sp0,  off); sp1  += __shfl_down(sp1,  off);
        sq0  += __shfl_down(sq0,  off); sq1  += __shfl_down(sq1,  off);
    }
    if (lane == 0) {
        partA[w][0] = sm00; partA[w][1] = sm01; partA[w][2] = sm10; partA[w][3] = sm11;
        partA[w][4] = sp0;  partA[w][5] = sp1;  partA[w][6] = sq0;  partA[w][7] = sq1;
    }

    // ---- phase B: wave w owns pair (a = w>>1, cj = w&1) ----
    {
        int a = w >> 1, cj = w & 1;
        const float* PX = sPx[a];  const float* PY = sPy[a];
        const float* GX = sGx[cj]; const float* GY = sGy[cj];
        float p0x = PX[lane], p0y = PY[lane];
        float q0x = GX[lane], q0y = GY[lane];
        float b1 = 1e30f, b2 = 1e30f;
        for (int s = 0; s < NRS - 1; s++) {
            {   // pred point -> gt segment s
                float ax = GX[s], ay = GY[s];
                float abx = GX[s + 1] - ax, aby = GY[s + 1] - ay;
                float denom = fmaxf(abx * abx + aby * aby, 1e-8f);
                float t = ((p0x - ax) * abx + (p0y - ay) * aby) / denom;
                t = fminf(fmaxf(t, 0.0f), 1.0f);
                float dx = p0x - (ax + t * abx), dy = p0y - (ay + t * aby);
                b1 = fminf(b1, dx * dx + dy * dy);
            }
            {   // gt point -> pred segment s
                float ax = PX[s], ay = PY[s];
                float abx = PX[s + 1] - ax, aby = PY[s + 1] - ay;
                float denom = fmaxf(abx * abx + aby * aby, 1e-8f);
                float t = ((q0x - ax) * abx + (q0y - ay) * aby) / denom;
                t = fminf(fmaxf(t, 0.0f), 1.0f);
                float dx = q0x - (ax + t * abx), dy = q0y - (ay + t * aby);
                b2 = fminf(b2, dx * dx + dy * dy);
            }
        }
        float symv = 0.5f * (sqrtf(b1) + sqrtf(b2));

        int kp = (lane == NRS - 1) ? NRS - 1 : lane + 1;
        int km = (lane == 0) ? 0 : lane - 1;
        float tx = PX[kp] - PX[km], ty = PY[kp] - PY[km];
        float nrm = fmaxf(sqrtf(tx * tx + ty * ty), 1e-8f);
        tx /= nrm; ty /= nrm;
        float gtx = GX[kp] - GX[km], gty = GY[kp] - GY[km];
        float nrm2 = fmaxf(sqrtf(gtx * gtx + gty * gty), 1e-8f);
        gtx /= nrm2; gty /= nrm2;
        float tanv = fabsf(tx * gtx + ty * gty);

        float curvv = 0.0f;
        if (lane < NRS - 2) {
            float psx = PX[lane + 2] - 2.0f * PX[lane + 1] + PX[lane];
            float psy = PY[lane + 2] - 2.0f * PY[lane + 1] + PY[lane];
            float gsx = GX[lane + 2] - 2.0f * GX[lane + 1] + GX[lane];
            float gsy = GY[lane + 2] - 2.0f * GY[lane + 1] + GY[lane];
            float d1 = fabsf(psx - gsx);
            float d2 = fabsf(psy - gsy);
            float c1 = (d1 < 1.0f) ? 0.5f * d1 * d1 : d1 - 0.5f;
            float c2 = (d2 < 1.0f) ? 0.5f * d2 * d2 : d2 - 0.5f;
            curvv = c1 + c2;
        }
        for (int off = 32; off > 0; off >>= 1) {
            symv  += __shfl_down(symv,  off);
            tanv  += __shfl_down(tanv,  off);
            curvv += __shfl_down(curvv, off);
        }
        if (lane == 0) { cham[w][0] = symv; cham[w][1] = tanv; cham[w][2] = curvv; }
    }
    __syncthreads();

    if (tid < 4) {
        int a2 = tid >> 1, c2 = tid & 1;
        float Smin = partA[0][tid] + partA[1][tid] + partA[2][tid] + partA[3][tid];
        float Sp = partA[0][4 + a2] + partA[1][4 + a2] + partA[2][4 + a2] + partA[3][4 + a2];
        float Sq = partA[0][6 + c2] + partA[1][6 + c2] + partA[2][6 + c2] + partA[3][6 + c2];
        float Smax = Sp + Sq - Smin;          // min+max == p+q
        float overlap = 1.0f - Smin / (Smax + 1e-8f);
        float sym  = cham[tid][0] * (1.0f / 64.0f);
        float tanl = 1.0f - cham[tid][1] * (1.0f / 64.0f);
        float curv = cham[tid][2] * (1.0f / 124.0f);
        float cost = 5.0f * sym + 1.0f * tanl + 0.5f * curv + 2.0f * overlap;
        float e = (gtExist[b * Ng + j0 + c2] > 0.5f) ? 1.0f : 0.0f;
        out[(size_t)(b * Mp + i0 + a2) * Ng + j0 + c2] = cost * e;
    }
}

// ---------------------------------------------------------------------------
extern "C" void kernel_launch(void* const* d_in, const int* in_sizes, int n_in,
                              void* d_out, int out_size, void* d_ws, size_t ws_size,
                              hipStream_t stream) {
    (void)in_sizes; (void)n_in; (void)out_size; (void)ws_size;
    const float* pred  = (const float*)d_in[0];   // (2,40,24,2)
    const float* gt    = (const float*)d_in[1];   // (2,24,24,2)
    const float* vis   = (const float*)d_in[2];   // (2,24,24)
    const float* exist = (const float*)d_in[3];   // (2,24)

    float* ws      = (float*)d_ws;
    float* predRS  = ws;                                   // 10240
    float* gtRS    = predRS + (size_t)Bb * Mp * NRS * 2;   // 6144
    float* maskAll = gtRS   + (size_t)Bb * Ng * NRS * 2;   // 128*9216 floats
    float* outp    = (float*)d_out;

    hipLaunchKernelGGL(k_mask, dim3(XBLK, NCURV), dim3(256), 0, stream,
                       pred, gt, vis, predRS, gtRS, maskAll);
    hipLaunchKernelGGL(k_cost, dim3(Bb * 20 * 12), dim3(256), 0, stream,
                       predRS, gtRS, maskAll, exist, outp);
}